// Round 4
// baseline (29.606 us; speedup 1.0000x reference)
//
#include <hip/hip_runtime.h>

#define NN 4096
#define MM 4096
#define PP 32

typedef short bf16x8 __attribute__((ext_vector_type(8)));
typedef float f32x4  __attribute__((ext_vector_type(4)));

// ws layout (ushort elements): x1h[NN*PP] | x1l[NN*PP] | x2h[MM*PP] | x2l[MM*PP]
// then (float) norms: xn[NN] | yn[MM]   -- total ~1.06 MB
#define WS_X1H 0
#define WS_X1L (NN * PP)
#define WS_X2H (2 * NN * PP)
#define WS_X2L (2 * NN * PP + MM * PP)
#define WS_NORM_U16 (2 * NN * PP + 2 * MM * PP)   // ushort offset where floats begin

__device__ __forceinline__ unsigned short f32_to_bf16_rtn(float f) {
    unsigned u = __float_as_uint(f);
    u += 0x7FFF + ((u >> 16) & 1);
    return (unsigned short)(u >> 16);
}

// ---------------------------------------------------------------------------
// Prep: per row, split f32 -> (hi, lo) bf16 pair and compute fp32 row norm.
// 8192 threads, 1 row each. Tiny (reads 1 MB writes 1.06 MB, L2-resident).
// ---------------------------------------------------------------------------
__global__ void eq_prep_kernel(const float* __restrict__ x1,
                               const float* __restrict__ x2,
                               unsigned short* __restrict__ wsu,
                               float* __restrict__ norms) {
    int t = blockIdx.x * blockDim.x + threadIdx.x;
    if (t >= NN + MM) return;
    int row = (t < NN) ? t : t - NN;
    const float* srow = ((t < NN) ? x1 : x2) + row * PP;
    unsigned short* hrow = wsu + ((t < NN) ? WS_X1H : WS_X2H) + row * PP;
    unsigned short* lrow = wsu + ((t < NN) ? WS_X1L : WS_X2L) + row * PP;

    float s = 0.f;
#pragma unroll
    for (int k = 0; k < 4; ++k) {
        float4 a = *reinterpret_cast<const float4*>(srow + k * 8);
        float4 b = *reinterpret_cast<const float4*>(srow + k * 8 + 4);
        float vs[8] = {a.x, a.y, a.z, a.w, b.x, b.y, b.z, b.w};
        bf16x8 hv, lv;
#pragma unroll
        for (int e = 0; e < 8; ++e) {
            float v = vs[e];
            s = fmaf(v, v, s);
            unsigned short h = f32_to_bf16_rtn(v);
            float hf = __uint_as_float((unsigned)h << 16);
            hv[e] = (short)h;
            lv[e] = (short)f32_to_bf16_rtn(v - hf);
        }
        *reinterpret_cast<bf16x8*>(hrow + k * 8) = hv;
        *reinterpret_cast<bf16x8*>(lrow + k * 8) = lv;
    }
    norms[t] = s;
}

// ---------------------------------------------------------------------------
// Main: 128x128 tile / block (4 waves). Wave w owns rows w*32..w*32+31
// (2 strips of 16) x all 128 cols (8 col-tiles of 16).
// Per 16x16 tile: dot = one mfma_f32_16x16x32_bf16 triple (hh, hl, lh) --
// K=32=PP, so no K loop. Fragments are contiguous 16B row chunks of the
// bf16 panels, loaded straight from L2 (no LDS for operands).
// C/D layout (m89-verified): col = lane&15, row = (lane>>4)*4 + reg.
// Epilogue per tile: d = (xn+yn)*ir2 - 2*ir2*dot, clamp, K = sigma*exp(-d/2),
// nontemporal dword stores (keep bf16 panels L2-resident vs 64MB stream).
// ---------------------------------------------------------------------------
__launch_bounds__(256, 4)
__global__ void eq_mfma_kernel(const unsigned short* __restrict__ wsu,
                               const float* __restrict__ norms,
                               const float* __restrict__ log_rho,
                               const float* __restrict__ log_sigma,
                               float* __restrict__ out) {
    __shared__ float xn_s[128];
    __shared__ float yn_s[128];

    const int t  = threadIdx.x;
    const int bx = blockIdx.x;
    const int by = blockIdx.y;

    if (t < 128) xn_s[t] = norms[by * 128 + t];
    else         yn_s[t - 128] = norms[NN + bx * 128 + (t - 128)];

    const int w    = t >> 6;   // wave 0..3
    const int l    = t & 63;
    const int lo16 = l & 15;
    const int kg   = l >> 4;   // k-group 0..3

    const unsigned short* x1h = wsu + WS_X1H;
    const unsigned short* x1l = wsu + WS_X1L;
    const unsigned short* x2h = wsu + WS_X2H;
    const unsigned short* x2l = wsu + WS_X2L;

    const int rbase = by * 128 + w * 32;

    // A fragments for the wave's two 16-row strips (hi and lo planes)
    bf16x8 ah[2], al[2];
#pragma unroll
    for (int s = 0; s < 2; ++s) {
        int row = rbase + s * 16 + lo16;
        ah[s] = *reinterpret_cast<const bf16x8*>(x1h + row * PP + kg * 8);
        al[s] = *reinterpret_cast<const bf16x8*>(x1l + row * PP + kg * 8);
    }

    const float inv_rho2 = __expf(-2.f * log_rho[0]);
    const float sigma    = __expf(2.f * log_sigma[0]);
    const float m2ir2    = -2.f * inv_rho2;

    __syncthreads();

    const int cb0 = bx * 128;
#pragma unroll
    for (int ct = 0; ct < 8; ++ct) {
        const int colrow = cb0 + ct * 16 + lo16;
        bf16x8 bh = *reinterpret_cast<const bf16x8*>(x2h + colrow * PP + kg * 8);
        bf16x8 bl = *reinterpret_cast<const bf16x8*>(x2l + colrow * PP + kg * 8);
        const float ynv = yn_s[ct * 16 + lo16] * inv_rho2;
#pragma unroll
        for (int s = 0; s < 2; ++s) {
            f32x4 acc = {0.f, 0.f, 0.f, 0.f};
            acc = __builtin_amdgcn_mfma_f32_16x16x32_bf16(ah[s], bh, acc, 0, 0, 0);
            acc = __builtin_amdgcn_mfma_f32_16x16x32_bf16(ah[s], bl, acc, 0, 0, 0);
            acc = __builtin_amdgcn_mfma_f32_16x16x32_bf16(al[s], bh, acc, 0, 0, 0);
#pragma unroll
            for (int r = 0; r < 4; ++r) {
                float xnv = xn_s[w * 32 + s * 16 + kg * 4 + r] * inv_rho2;
                float d = fmaf(m2ir2, acc[r], xnv + ynv);
                d = fmaxf(d, 0.f);
                float K = sigma * __expf(-0.5f * d);
                int row = rbase + s * 16 + kg * 4 + r;
                __builtin_nontemporal_store(K, &out[row * MM + cb0 + ct * 16 + lo16]);
            }
        }
    }
}

extern "C" void kernel_launch(void* const* d_in, const int* in_sizes, int n_in,
                              void* d_out, int out_size, void* d_ws, size_t ws_size,
                              hipStream_t stream) {
    const float* x1        = (const float*)d_in[0];
    const float* x2        = (const float*)d_in[1];
    const float* log_rho   = (const float*)d_in[2];
    const float* log_sigma = (const float*)d_in[3];
    float* out = (float*)d_out;

    unsigned short* wsu = (unsigned short*)d_ws;
    float* norms = (float*)(wsu + WS_NORM_U16);

    eq_prep_kernel<<<(NN + MM + 255) / 256, 256, 0, stream>>>(x1, x2, wsu, norms);

    dim3 grid(MM / 128, NN / 128);   // 32 x 32 = 1024 blocks
    eq_mfma_kernel<<<grid, 256, 0, stream>>>(wsu, norms, log_rho, log_sigma, out);
}

// Round 5
// 26.242 us; speedup vs baseline: 1.1282x; 1.1282x over previous
//
#include <hip/hip_runtime.h>

#define NN 4096
#define MM 4096
#define PP 32
#define LDA 40   // ushort row stride in LDS (80 B): 16B-aligned, bank-balanced

typedef short bf16x8 __attribute__((ext_vector_type(8)));
typedef float f32x4  __attribute__((ext_vector_type(4)));

__device__ __forceinline__ unsigned short f32_to_bf16_rtn(float f) {
    unsigned u = __float_as_uint(f);
    u += 0x7FFF + ((u >> 16) & 1);
    return (unsigned short)(u >> 16);
}

// Single fused kernel: 128x128 tile / 256 threads (4 waves).
// Phase 1: stage split-bf16 (hi,lo) planes of the block's 128 x1-rows and
//          128 x2-rows into LDS + fp32 row norms (2-lane shfl reduce).
// Phase 2: dot via mfma_f32_16x16x32_bf16 triple (hh + hl + lh), K=32=PP so
//          no K-loop; epilogue d=(xn+yn-2dot)*ir2, K=sigma*exp(-d/2);
//          nontemporal dword stores (16-lane groups = 64B cachelines).
// C/D layout (m89-verified): col = lane&15, row = (lane>>4)*4 + reg.
__launch_bounds__(256, 3)
__global__ void eq_fused_mfma_kernel(const float* __restrict__ x1,
                                     const float* __restrict__ x2,
                                     const float* __restrict__ log_rho,
                                     const float* __restrict__ log_sigma,
                                     float* __restrict__ out) {
    __shared__ unsigned short Ah[128 * LDA];
    __shared__ unsigned short Al[128 * LDA];
    __shared__ unsigned short Bh[128 * LDA];
    __shared__ unsigned short Bl[128 * LDA];
    __shared__ float xn_s[128];
    __shared__ float yn_s[128];

    const int t  = threadIdx.x;
    const int bx = blockIdx.x;
    const int by = blockIdx.y;

    // ---------------- Phase 1: stage + split + norms ----------------
    {
        const int row  = t >> 1;       // 0..127
        const int half = t & 1;        // 16-elem half of the row
        // A panel
        {
            const float* src = x1 + (size_t)(by * 128 + row) * PP + half * 16;
            float partial = 0.f;
#pragma unroll
            for (int g = 0; g < 2; ++g) {
                float4 a = *reinterpret_cast<const float4*>(src + g * 8);
                float4 b = *reinterpret_cast<const float4*>(src + g * 8 + 4);
                float vs[8] = {a.x, a.y, a.z, a.w, b.x, b.y, b.z, b.w};
                bf16x8 hv, lv;
#pragma unroll
                for (int e = 0; e < 8; ++e) {
                    float v = vs[e];
                    partial = fmaf(v, v, partial);
                    unsigned short h = f32_to_bf16_rtn(v);
                    hv[e] = (short)h;
                    lv[e] = (short)f32_to_bf16_rtn(v - __uint_as_float((unsigned)h << 16));
                }
                int off = row * LDA + half * 16 + g * 8;
                *reinterpret_cast<bf16x8*>(&Ah[off]) = hv;
                *reinterpret_cast<bf16x8*>(&Al[off]) = lv;
            }
            float full = partial + __shfl_xor(partial, 1);
            if (half == 0) xn_s[row] = full;
        }
        // B panel
        {
            const float* src = x2 + (size_t)(bx * 128 + row) * PP + half * 16;
            float partial = 0.f;
#pragma unroll
            for (int g = 0; g < 2; ++g) {
                float4 a = *reinterpret_cast<const float4*>(src + g * 8);
                float4 b = *reinterpret_cast<const float4*>(src + g * 8 + 4);
                float vs[8] = {a.x, a.y, a.z, a.w, b.x, b.y, b.z, b.w};
                bf16x8 hv, lv;
#pragma unroll
                for (int e = 0; e < 8; ++e) {
                    float v = vs[e];
                    partial = fmaf(v, v, partial);
                    unsigned short h = f32_to_bf16_rtn(v);
                    hv[e] = (short)h;
                    lv[e] = (short)f32_to_bf16_rtn(v - __uint_as_float((unsigned)h << 16));
                }
                int off = row * LDA + half * 16 + g * 8;
                *reinterpret_cast<bf16x8*>(&Bh[off]) = hv;
                *reinterpret_cast<bf16x8*>(&Bl[off]) = lv;
            }
            float full = partial + __shfl_xor(partial, 1);
            if (half == 0) yn_s[row] = full;
        }
    }

    const float inv_rho2 = __expf(-2.f * log_rho[0]);
    const float sigma    = __expf(2.f * log_sigma[0]);
    const float m2ir2    = -2.f * inv_rho2;

    __syncthreads();

    // ---------------- Phase 2: MFMA + epilogue + store ----------------
    const int w    = t >> 6;   // wave 0..3 -> rows w*32..w*32+31
    const int l    = t & 63;
    const int lo16 = l & 15;
    const int kg   = l >> 4;   // k-group 0..3

    bf16x8 ah[2], al[2];
#pragma unroll
    for (int s = 0; s < 2; ++s) {
        int off = (w * 32 + s * 16 + lo16) * LDA + kg * 8;
        ah[s] = *reinterpret_cast<const bf16x8*>(&Ah[off]);
        al[s] = *reinterpret_cast<const bf16x8*>(&Al[off]);
    }

    float xnv[2][4];
#pragma unroll
    for (int s = 0; s < 2; ++s)
#pragma unroll
        for (int r = 0; r < 4; ++r)
            xnv[s][r] = xn_s[w * 32 + s * 16 + kg * 4 + r] * inv_rho2;

    const int rbase = by * 128 + w * 32;
    const int cb0   = bx * 128;

#pragma unroll
    for (int ct = 0; ct < 8; ++ct) {
        int off = (ct * 16 + lo16) * LDA + kg * 8;
        bf16x8 bh = *reinterpret_cast<const bf16x8*>(&Bh[off]);
        bf16x8 bl = *reinterpret_cast<const bf16x8*>(&Bl[off]);
        const float ynv = yn_s[ct * 16 + lo16] * inv_rho2;
        const int col = cb0 + ct * 16 + lo16;
#pragma unroll
        for (int s = 0; s < 2; ++s) {
            f32x4 acc = {0.f, 0.f, 0.f, 0.f};
            acc = __builtin_amdgcn_mfma_f32_16x16x32_bf16(ah[s], bh, acc, 0, 0, 0);
            acc = __builtin_amdgcn_mfma_f32_16x16x32_bf16(ah[s], bl, acc, 0, 0, 0);
            acc = __builtin_amdgcn_mfma_f32_16x16x32_bf16(al[s], bh, acc, 0, 0, 0);
#pragma unroll
            for (int r = 0; r < 4; ++r) {
                float d = fmaf(m2ir2, acc[r], xnv[s][r] + ynv);
                d = fmaxf(d, 0.f);
                float K = sigma * __expf(-0.5f * d);
                int row = rbase + s * 16 + kg * 4 + r;
                __builtin_nontemporal_store(K, &out[(size_t)row * MM + col]);
            }
        }
    }
}

extern "C" void kernel_launch(void* const* d_in, const int* in_sizes, int n_in,
                              void* d_out, int out_size, void* d_ws, size_t ws_size,
                              hipStream_t stream) {
    const float* x1        = (const float*)d_in[0];
    const float* x2        = (const float*)d_in[1];
    const float* log_rho   = (const float*)d_in[2];
    const float* log_sigma = (const float*)d_in[3];
    float* out = (float*)d_out;

    dim3 grid(MM / 128, NN / 128);   // 32 x 32 = 1024 blocks
    eq_fused_mfma_kernel<<<grid, 256, 0, stream>>>(x1, x2, log_rho, log_sigma, out);
}

// Round 7
// 24.099 us; speedup vs baseline: 1.2285x; 1.0889x over previous
//
#include <hip/hip_runtime.h>

#define NN 4096
#define MM 4096
#define PP 32
#define LDA 40   // ushort row stride in LDS (80 B): 16B-aligned, bank-balanced

typedef short bf16x8 __attribute__((ext_vector_type(8)));
typedef float f32x4  __attribute__((ext_vector_type(4)));

__device__ __forceinline__ unsigned short f32_to_bf16_rtn(float f) {
    unsigned u = __float_as_uint(f);
    u += 0x7FFF + ((u >> 16) & 1);
    return (unsigned short)(u >> 16);
}

// Single fused kernel: 128x128 tile / 256 threads (4 waves).
// Phase 1: stage split-bf16 (hi,lo) planes of the block's 128 x1-rows and
//          128 x2-rows into LDS + fp32 row norms (2-lane shfl reduce).
// Phase 2: dot via mfma_f32_16x16x32_bf16 with B-operand FIRST:
//          acc = mfma(b, a) transposes the C/D map so reg indexes the x2
//          (column) dim -> each lane holds 4 consecutive output columns of
//          one row -> ONE dwordx4 store per 16x16 tile (was 4 dword stores).
//          Epilogue in u-space: u = ir2*dot - 0.5*ir2*(xn+yn) = -d/2,
//          clamp u<=0, K = sigma*exp(u).
__launch_bounds__(256, 3)
__global__ void eq_fused_mfma_kernel(const float* __restrict__ x1,
                                     const float* __restrict__ x2,
                                     const float* __restrict__ log_rho,
                                     const float* __restrict__ log_sigma,
                                     float* __restrict__ out) {
    __shared__ unsigned short Ah[128 * LDA];
    __shared__ unsigned short Al[128 * LDA];
    __shared__ unsigned short Bh[128 * LDA];
    __shared__ unsigned short Bl[128 * LDA];
    __shared__ float xn_s[128];
    __shared__ float yn_s[128];

    const int t  = threadIdx.x;
    const int bx = blockIdx.x;
    const int by = blockIdx.y;

    // ---------------- Phase 1: stage + split + norms ----------------
    {
        const int row  = t >> 1;       // 0..127
        const int half = t & 1;        // 16-elem half of the row
        // A panel
        {
            const float* src = x1 + (size_t)(by * 128 + row) * PP + half * 16;
            float partial = 0.f;
#pragma unroll
            for (int g = 0; g < 2; ++g) {
                float4 a = *reinterpret_cast<const float4*>(src + g * 8);
                float4 b = *reinterpret_cast<const float4*>(src + g * 8 + 4);
                float vs[8] = {a.x, a.y, a.z, a.w, b.x, b.y, b.z, b.w};
                bf16x8 hv, lv;
#pragma unroll
                for (int e = 0; e < 8; ++e) {
                    float v = vs[e];
                    partial = fmaf(v, v, partial);
                    unsigned short h = f32_to_bf16_rtn(v);
                    hv[e] = (short)h;
                    lv[e] = (short)f32_to_bf16_rtn(v - __uint_as_float((unsigned)h << 16));
                }
                int off = row * LDA + half * 16 + g * 8;
                *reinterpret_cast<bf16x8*>(&Ah[off]) = hv;
                *reinterpret_cast<bf16x8*>(&Al[off]) = lv;
            }
            float full = partial + __shfl_xor(partial, 1);
            if (half == 0) xn_s[row] = full;
        }
        // B panel
        {
            const float* src = x2 + (size_t)(bx * 128 + row) * PP + half * 16;
            float partial = 0.f;
#pragma unroll
            for (int g = 0; g < 2; ++g) {
                float4 a = *reinterpret_cast<const float4*>(src + g * 8);
                float4 b = *reinterpret_cast<const float4*>(src + g * 8 + 4);
                float vs[8] = {a.x, a.y, a.z, a.w, b.x, b.y, b.z, b.w};
                bf16x8 hv, lv;
#pragma unroll
                for (int e = 0; e < 8; ++e) {
                    float v = vs[e];
                    partial = fmaf(v, v, partial);
                    unsigned short h = f32_to_bf16_rtn(v);
                    hv[e] = (short)h;
                    lv[e] = (short)f32_to_bf16_rtn(v - __uint_as_float((unsigned)h << 16));
                }
                int off = row * LDA + half * 16 + g * 8;
                *reinterpret_cast<bf16x8*>(&Bh[off]) = hv;
                *reinterpret_cast<bf16x8*>(&Bl[off]) = lv;
            }
            float full = partial + __shfl_xor(partial, 1);
            if (half == 0) yn_s[row] = full;
        }
    }

    const float inv_rho2 = __expf(-2.f * log_rho[0]);
    const float sigma    = __expf(2.f * log_sigma[0]);
    const float nh_ir2   = -0.5f * inv_rho2;

    __syncthreads();

    // ---------------- Phase 2: MFMA + epilogue + wide store ----------------
    const int w    = t >> 6;   // wave 0..3 -> rows w*32..w*32+31
    const int l    = t & 63;
    const int lo16 = l & 15;   // output ROW within strip (swapped layout)
    const int kg   = l >> 4;   // output col-quad within tile / k-chunk

    bf16x8 ah[2], al[2];
#pragma unroll
    for (int s = 0; s < 2; ++s) {
        int off = (w * 32 + s * 16 + lo16) * LDA + kg * 8;
        ah[s] = *reinterpret_cast<const bf16x8*>(&Ah[off]);
        al[s] = *reinterpret_cast<const bf16x8*>(&Al[off]);
    }

    float xh[2];   // -0.5*ir2*xn for this lane's row in each strip
#pragma unroll
    for (int s = 0; s < 2; ++s)
        xh[s] = nh_ir2 * xn_s[w * 32 + s * 16 + lo16];

    const int rbase = by * 128 + w * 32;
    const int cb0   = bx * 128;

#pragma unroll
    for (int ct = 0; ct < 8; ++ct) {
        int off = (ct * 16 + lo16) * LDA + kg * 8;
        bf16x8 bh = *reinterpret_cast<const bf16x8*>(&Bh[off]);
        bf16x8 bl = *reinterpret_cast<const bf16x8*>(&Bl[off]);
        float4 yn4 = *reinterpret_cast<const float4*>(&yn_s[ct * 16 + kg * 4]);
        float yh[4] = {nh_ir2 * yn4.x, nh_ir2 * yn4.y, nh_ir2 * yn4.z, nh_ir2 * yn4.w};
        const int colbase = cb0 + ct * 16 + kg * 4;
#pragma unroll
        for (int s = 0; s < 2; ++s) {
            f32x4 acc = {0.f, 0.f, 0.f, 0.f};
            // swapped operands: reg indexes x2 (column) dim
            acc = __builtin_amdgcn_mfma_f32_16x16x32_bf16(bh, ah[s], acc, 0, 0, 0);
            acc = __builtin_amdgcn_mfma_f32_16x16x32_bf16(bh, al[s], acc, 0, 0, 0);
            acc = __builtin_amdgcn_mfma_f32_16x16x32_bf16(bl, ah[s], acc, 0, 0, 0);
            f32x4 K;
            float u0 = fminf(fmaf(inv_rho2, acc[0], xh[s] + yh[0]), 0.f);
            float u1 = fminf(fmaf(inv_rho2, acc[1], xh[s] + yh[1]), 0.f);
            float u2 = fminf(fmaf(inv_rho2, acc[2], xh[s] + yh[2]), 0.f);
            float u3 = fminf(fmaf(inv_rho2, acc[3], xh[s] + yh[3]), 0.f);
            K[0] = sigma * __expf(u0);
            K[1] = sigma * __expf(u1);
            K[2] = sigma * __expf(u2);
            K[3] = sigma * __expf(u3);
            const int row = rbase + s * 16 + lo16;
            __builtin_nontemporal_store(K, reinterpret_cast<f32x4*>(&out[(size_t)row * MM + colbase]));
        }
    }
}

extern "C" void kernel_launch(void* const* d_in, const int* in_sizes, int n_in,
                              void* d_out, int out_size, void* d_ws, size_t ws_size,
                              hipStream_t stream) {
    const float* x1        = (const float*)d_in[0];
    const float* x2        = (const float*)d_in[1];
    const float* log_rho   = (const float*)d_in[2];
    const float* log_sigma = (const float*)d_in[3];
    float* out = (float*)d_out;

    dim3 grid(MM / 128, NN / 128);   // 32 x 32 = 1024 blocks
    eq_fused_mfma_kernel<<<grid, 256, 0, stream>>>(x1, x2, log_rho, log_sigma, out);
}

// Round 8
// 20.262 us; speedup vs baseline: 1.4611x; 1.1893x over previous
//
#include <hip/hip_runtime.h>

#define NN 4096
#define MM 4096
#define PP 32
#define LDA 40   // ushort row stride in LDS (80 B): 16B-aligned, bank-balanced

typedef short bf16x8 __attribute__((ext_vector_type(8)));
typedef float f32x4  __attribute__((ext_vector_type(4)));

__device__ __forceinline__ unsigned short f32_to_bf16_rtn(float f) {
    unsigned u = __float_as_uint(f);
    u += 0x7FFF + ((u >> 16) & 1);
    return (unsigned short)(u >> 16);
}

// Single fused kernel: 128x128 tile / 256 threads (4 waves).
// Phase 1: stage split-bf16 (hi,lo) planes of the block's 128 x1-rows and
//          128 x2-rows into LDS + fp32 row norms (2-lane shfl reduce).
// Phase 2: dot via mfma_f32_16x16x32_bf16 with swapped operands (reg indexes
//          the x2/column dim) -> one dwordx4 store per 16x16 tile.
//          Epilogue in u-space: u = ir2*dot - 0.5*ir2*(xn+yn) = -d/2,
//          clamp u<=0, K = sigma*exp(u).
// R8 A/B: plain (temporal) stores instead of nontemporal — let L2 combine the
//          16-row x 64B chunks into full lines (fills prove 6.2 TB/s this way).
__launch_bounds__(256, 3)
__global__ void eq_fused_mfma_kernel(const float* __restrict__ x1,
                                     const float* __restrict__ x2,
                                     const float* __restrict__ log_rho,
                                     const float* __restrict__ log_sigma,
                                     float* __restrict__ out) {
    __shared__ unsigned short Ah[128 * LDA];
    __shared__ unsigned short Al[128 * LDA];
    __shared__ unsigned short Bh[128 * LDA];
    __shared__ unsigned short Bl[128 * LDA];
    __shared__ float xn_s[128];
    __shared__ float yn_s[128];

    const int t  = threadIdx.x;
    const int bx = blockIdx.x;
    const int by = blockIdx.y;

    // ---------------- Phase 1: stage + split + norms ----------------
    {
        const int row  = t >> 1;       // 0..127
        const int half = t & 1;        // 16-elem half of the row
        // A panel
        {
            const float* src = x1 + (size_t)(by * 128 + row) * PP + half * 16;
            float partial = 0.f;
#pragma unroll
            for (int g = 0; g < 2; ++g) {
                float4 a = *reinterpret_cast<const float4*>(src + g * 8);
                float4 b = *reinterpret_cast<const float4*>(src + g * 8 + 4);
                float vs[8] = {a.x, a.y, a.z, a.w, b.x, b.y, b.z, b.w};
                bf16x8 hv, lv;
#pragma unroll
                for (int e = 0; e < 8; ++e) {
                    float v = vs[e];
                    partial = fmaf(v, v, partial);
                    unsigned short h = f32_to_bf16_rtn(v);
                    hv[e] = (short)h;
                    lv[e] = (short)f32_to_bf16_rtn(v - __uint_as_float((unsigned)h << 16));
                }
                int off = row * LDA + half * 16 + g * 8;
                *reinterpret_cast<bf16x8*>(&Ah[off]) = hv;
                *reinterpret_cast<bf16x8*>(&Al[off]) = lv;
            }
            float full = partial + __shfl_xor(partial, 1);
            if (half == 0) xn_s[row] = full;
        }
        // B panel
        {
            const float* src = x2 + (size_t)(bx * 128 + row) * PP + half * 16;
            float partial = 0.f;
#pragma unroll
            for (int g = 0; g < 2; ++g) {
                float4 a = *reinterpret_cast<const float4*>(src + g * 8);
                float4 b = *reinterpret_cast<const float4*>(src + g * 8 + 4);
                float vs[8] = {a.x, a.y, a.z, a.w, b.x, b.y, b.z, b.w};
                bf16x8 hv, lv;
#pragma unroll
                for (int e = 0; e < 8; ++e) {
                    float v = vs[e];
                    partial = fmaf(v, v, partial);
                    unsigned short h = f32_to_bf16_rtn(v);
                    hv[e] = (short)h;
                    lv[e] = (short)f32_to_bf16_rtn(v - __uint_as_float((unsigned)h << 16));
                }
                int off = row * LDA + half * 16 + g * 8;
                *reinterpret_cast<bf16x8*>(&Bh[off]) = hv;
                *reinterpret_cast<bf16x8*>(&Bl[off]) = lv;
            }
            float full = partial + __shfl_xor(partial, 1);
            if (half == 0) yn_s[row] = full;
        }
    }

    const float inv_rho2 = __expf(-2.f * log_rho[0]);
    const float sigma    = __expf(2.f * log_sigma[0]);
    const float nh_ir2   = -0.5f * inv_rho2;

    __syncthreads();

    // ---------------- Phase 2: MFMA + epilogue + wide store ----------------
    const int w    = t >> 6;   // wave 0..3 -> rows w*32..w*32+31
    const int l    = t & 63;
    const int lo16 = l & 15;   // output ROW within strip (swapped layout)
    const int kg   = l >> 4;   // output col-quad within tile / k-chunk

    bf16x8 ah[2], al[2];
#pragma unroll
    for (int s = 0; s < 2; ++s) {
        int off = (w * 32 + s * 16 + lo16) * LDA + kg * 8;
        ah[s] = *reinterpret_cast<const bf16x8*>(&Ah[off]);
        al[s] = *reinterpret_cast<const bf16x8*>(&Al[off]);
    }

    float xh[2];   // -0.5*ir2*xn for this lane's row in each strip
#pragma unroll
    for (int s = 0; s < 2; ++s)
        xh[s] = nh_ir2 * xn_s[w * 32 + s * 16 + lo16];

    const int rbase = by * 128 + w * 32;
    const int cb0   = bx * 128;

#pragma unroll
    for (int ct = 0; ct < 8; ++ct) {
        int off = (ct * 16 + lo16) * LDA + kg * 8;
        bf16x8 bh = *reinterpret_cast<const bf16x8*>(&Bh[off]);
        bf16x8 bl = *reinterpret_cast<const bf16x8*>(&Bl[off]);
        float4 yn4 = *reinterpret_cast<const float4*>(&yn_s[ct * 16 + kg * 4]);
        float yh[4] = {nh_ir2 * yn4.x, nh_ir2 * yn4.y, nh_ir2 * yn4.z, nh_ir2 * yn4.w};
        const int colbase = cb0 + ct * 16 + kg * 4;
#pragma unroll
        for (int s = 0; s < 2; ++s) {
            f32x4 acc = {0.f, 0.f, 0.f, 0.f};
            // swapped operands: reg indexes x2 (column) dim
            acc = __builtin_amdgcn_mfma_f32_16x16x32_bf16(bh, ah[s], acc, 0, 0, 0);
            acc = __builtin_amdgcn_mfma_f32_16x16x32_bf16(bh, al[s], acc, 0, 0, 0);
            acc = __builtin_amdgcn_mfma_f32_16x16x32_bf16(bl, ah[s], acc, 0, 0, 0);
            f32x4 K;
            float u0 = fminf(fmaf(inv_rho2, acc[0], xh[s] + yh[0]), 0.f);
            float u1 = fminf(fmaf(inv_rho2, acc[1], xh[s] + yh[1]), 0.f);
            float u2 = fminf(fmaf(inv_rho2, acc[2], xh[s] + yh[2]), 0.f);
            float u3 = fminf(fmaf(inv_rho2, acc[3], xh[s] + yh[3]), 0.f);
            K[0] = sigma * __expf(u0);
            K[1] = sigma * __expf(u1);
            K[2] = sigma * __expf(u2);
            K[3] = sigma * __expf(u3);
            const int row = rbase + s * 16 + lo16;
            *reinterpret_cast<f32x4*>(&out[(size_t)row * MM + colbase]) = K;
        }
    }
}

extern "C" void kernel_launch(void* const* d_in, const int* in_sizes, int n_in,
                              void* d_out, int out_size, void* d_ws, size_t ws_size,
                              hipStream_t stream) {
    const float* x1        = (const float*)d_in[0];
    const float* x2        = (const float*)d_in[1];
    const float* log_rho   = (const float*)d_in[2];
    const float* log_sigma = (const float*)d_in[3];
    float* out = (float*)d_out;

    dim3 grid(MM / 128, NN / 128);   // 32 x 32 = 1024 blocks
    eq_fused_mfma_kernel<<<grid, 256, 0, stream>>>(x1, x2, log_rho, log_sigma, out);
}

// Round 9
// 19.600 us; speedup vs baseline: 1.5105x; 1.0338x over previous
//
#include <hip/hip_runtime.h>

#define NN 4096
#define MM 4096
#define PP 32
#define LDA 40   // ushort row stride in LDS (80 B): 16B-aligned, bank-balanced
                 // ushorts 32..33 of each row hold the row's fp32 norm (overlay)

typedef short bf16x8 __attribute__((ext_vector_type(8)));
typedef float f32x4  __attribute__((ext_vector_type(4)));

__device__ __forceinline__ unsigned short f32_to_bf16_rtn(float f) {
    unsigned u = __float_as_uint(f);
    u += 0x7FFF + ((u >> 16) & 1);
    return (unsigned short)(u >> 16);
}

// Single fused kernel: 128x128 tile / 256 threads (4 waves).
// LDS = 4 panels x 128 x 40 ushorts = 40,960 B exactly -> 4 blocks/CU
// (160 KiB fully used), grid 1024 = 256 CU x 4 -> ALL blocks resident, no tail.
// Norms live in the panels' 16B/row padding (fp32 at ushort offset 32).
// Phase 2: mfma_f32_16x16x32_bf16, swapped operands (reg indexes x2/column) ->
// one plain dwordx4 store per 16x16 tile. u-space epilogue, K = sigma*exp(u).
__launch_bounds__(256, 4)
__global__ void eq_fused_mfma_kernel(const float* __restrict__ x1,
                                     const float* __restrict__ x2,
                                     const float* __restrict__ log_rho,
                                     const float* __restrict__ log_sigma,
                                     float* __restrict__ out) {
    __shared__ unsigned short Ah[128 * LDA];
    __shared__ unsigned short Al[128 * LDA];
    __shared__ unsigned short Bh[128 * LDA];
    __shared__ unsigned short Bl[128 * LDA];

    const int t  = threadIdx.x;
    const int bx = blockIdx.x;
    const int by = blockIdx.y;

    // ---------------- Phase 1: stage + split + norms ----------------
    {
        const int row  = t >> 1;       // 0..127
        const int half = t & 1;        // 16-elem half of the row
        // A panel
        {
            const float* src = x1 + (size_t)(by * 128 + row) * PP + half * 16;
            float partial = 0.f;
#pragma unroll
            for (int g = 0; g < 2; ++g) {
                float4 a = *reinterpret_cast<const float4*>(src + g * 8);
                float4 b = *reinterpret_cast<const float4*>(src + g * 8 + 4);
                float vs[8] = {a.x, a.y, a.z, a.w, b.x, b.y, b.z, b.w};
                bf16x8 hv, lv;
#pragma unroll
                for (int e = 0; e < 8; ++e) {
                    float v = vs[e];
                    partial = fmaf(v, v, partial);
                    unsigned short h = f32_to_bf16_rtn(v);
                    hv[e] = (short)h;
                    lv[e] = (short)f32_to_bf16_rtn(v - __uint_as_float((unsigned)h << 16));
                }
                int off = row * LDA + half * 16 + g * 8;
                *reinterpret_cast<bf16x8*>(&Ah[off]) = hv;
                *reinterpret_cast<bf16x8*>(&Al[off]) = lv;
            }
            float full = partial + __shfl_xor(partial, 1);
            if (half == 0) *reinterpret_cast<float*>(&Ah[row * LDA + 32]) = full;
        }
        // B panel
        {
            const float* src = x2 + (size_t)(bx * 128 + row) * PP + half * 16;
            float partial = 0.f;
#pragma unroll
            for (int g = 0; g < 2; ++g) {
                float4 a = *reinterpret_cast<const float4*>(src + g * 8);
                float4 b = *reinterpret_cast<const float4*>(src + g * 8 + 4);
                float vs[8] = {a.x, a.y, a.z, a.w, b.x, b.y, b.z, b.w};
                bf16x8 hv, lv;
#pragma unroll
                for (int e = 0; e < 8; ++e) {
                    float v = vs[e];
                    partial = fmaf(v, v, partial);
                    unsigned short h = f32_to_bf16_rtn(v);
                    hv[e] = (short)h;
                    lv[e] = (short)f32_to_bf16_rtn(v - __uint_as_float((unsigned)h << 16));
                }
                int off = row * LDA + half * 16 + g * 8;
                *reinterpret_cast<bf16x8*>(&Bh[off]) = hv;
                *reinterpret_cast<bf16x8*>(&Bl[off]) = lv;
            }
            float full = partial + __shfl_xor(partial, 1);
            if (half == 0) *reinterpret_cast<float*>(&Bh[row * LDA + 32]) = full;
        }
    }

    const float inv_rho2 = __expf(-2.f * log_rho[0]);
    const float sigma    = __expf(2.f * log_sigma[0]);
    const float nh_ir2   = -0.5f * inv_rho2;

    __syncthreads();

    // ---------------- Phase 2: MFMA + epilogue + wide store ----------------
    const int w    = t >> 6;   // wave 0..3 -> rows w*32..w*32+31
    const int l    = t & 63;
    const int lo16 = l & 15;   // output ROW within strip (swapped layout)
    const int kg   = l >> 4;   // output col-quad within tile / k-chunk

    bf16x8 ah[2], al[2];
    float xh[2];               // -0.5*ir2*xn for this lane's row in each strip
#pragma unroll
    for (int s = 0; s < 2; ++s) {
        int r   = w * 32 + s * 16 + lo16;
        int off = r * LDA + kg * 8;
        ah[s] = *reinterpret_cast<const bf16x8*>(&Ah[off]);
        al[s] = *reinterpret_cast<const bf16x8*>(&Al[off]);
        xh[s] = nh_ir2 * *reinterpret_cast<const float*>(&Ah[r * LDA + 32]);
    }

    const int rbase = by * 128 + w * 32;
    const int cb0   = bx * 128;

#pragma unroll
    for (int ct = 0; ct < 8; ++ct) {
        int off = (ct * 16 + lo16) * LDA + kg * 8;
        bf16x8 bh = *reinterpret_cast<const bf16x8*>(&Bh[off]);
        bf16x8 bl = *reinterpret_cast<const bf16x8*>(&Bl[off]);
        float yh[4];
#pragma unroll
        for (int j = 0; j < 4; ++j)   // uniform across 16-lane group -> broadcast
            yh[j] = nh_ir2 * *reinterpret_cast<const float*>(&Bh[(ct * 16 + kg * 4 + j) * LDA + 32]);
        const int colbase = cb0 + ct * 16 + kg * 4;
#pragma unroll
        for (int s = 0; s < 2; ++s) {
            f32x4 acc = {0.f, 0.f, 0.f, 0.f};
            // swapped operands: reg indexes x2 (column) dim
            acc = __builtin_amdgcn_mfma_f32_16x16x32_bf16(bh, ah[s], acc, 0, 0, 0);
            acc = __builtin_amdgcn_mfma_f32_16x16x32_bf16(bh, al[s], acc, 0, 0, 0);
            acc = __builtin_amdgcn_mfma_f32_16x16x32_bf16(bl, ah[s], acc, 0, 0, 0);
            f32x4 K;
            float u0 = fminf(fmaf(inv_rho2, acc[0], xh[s] + yh[0]), 0.f);
            float u1 = fminf(fmaf(inv_rho2, acc[1], xh[s] + yh[1]), 0.f);
            float u2 = fminf(fmaf(inv_rho2, acc[2], xh[s] + yh[2]), 0.f);
            float u3 = fminf(fmaf(inv_rho2, acc[3], xh[s] + yh[3]), 0.f);
            K[0] = sigma * __expf(u0);
            K[1] = sigma * __expf(u1);
            K[2] = sigma * __expf(u2);
            K[3] = sigma * __expf(u3);
            const int row = rbase + s * 16 + lo16;
            *reinterpret_cast<f32x4*>(&out[(size_t)row * MM + colbase]) = K;
        }
    }
}

extern "C" void kernel_launch(void* const* d_in, const int* in_sizes, int n_in,
                              void* d_out, int out_size, void* d_ws, size_t ws_size,
                              hipStream_t stream) {
    const float* x1        = (const float*)d_in[0];
    const float* x2        = (const float*)d_in[1];
    const float* log_rho   = (const float*)d_in[2];
    const float* log_sigma = (const float*)d_in[3];
    float* out = (float*)d_out;

    dim3 grid(MM / 128, NN / 128);   // 32 x 32 = 1024 blocks = 256 CU x 4
    eq_fused_mfma_kernel<<<grid, 256, 0, stream>>>(x1, x2, log_rho, log_sigma, out);
}

// Round 10
// 19.514 us; speedup vs baseline: 1.5172x; 1.0044x over previous
//
#include <hip/hip_runtime.h>

#define NN 4096
#define MM 4096
#define PP 32
#define LDA 40   // ushort row stride in LDS (80 B): 16B-aligned, bank-balanced
                 // ushorts 32..33 of each row hold the row's fp32 norm (overlay)

typedef short bf16x8 __attribute__((ext_vector_type(8)));
typedef float f32x4  __attribute__((ext_vector_type(4)));

#define LOG2E 1.44269504088896f

__device__ __forceinline__ unsigned short f32_to_bf16_rtn(float f) {
    unsigned u = __float_as_uint(f);
    u += 0x7FFF + ((u >> 16) & 1);
    return (unsigned short)(u >> 16);
}

// Single fused kernel: 128x128 tile / 256 threads (4 waves), 40,960 B LDS
// -> 4 blocks/CU, grid 1024 = all blocks resident (no tail).
// R10: (a) split-B staging: B rows 0-63 staged before sync1, rows 64-127
//      written after sync1 and consumed after sync2 -> ct 0-3 compute/stores
//      overlap B1's LDS writes; (b) exp2-space epilogue: fold LOG2E and
//      log2(sigma) into the fmaf constants -> K = exp2(min(u', ls2)),
//      4 -> 3 VALU + 1 trans per output.
__launch_bounds__(256, 4)
__global__ void eq_fused_mfma_kernel(const float* __restrict__ x1,
                                     const float* __restrict__ x2,
                                     const float* __restrict__ log_rho,
                                     const float* __restrict__ log_sigma,
                                     float* __restrict__ out) {
    __shared__ unsigned short Ah[128 * LDA];
    __shared__ unsigned short Al[128 * LDA];
    __shared__ unsigned short Bh[128 * LDA];
    __shared__ unsigned short Bl[128 * LDA];

    const int t  = threadIdx.x;
    const int bx = blockIdx.x;
    const int by = blockIdx.y;

    const int row  = t >> 1;       // 0..127
    const int half = t & 1;        // 16-elem half of the row

    // ---- issue B-row global loads early (latency hides under A staging) ----
    const float* srcB = x2 + (size_t)(bx * 128 + row) * PP + half * 16;
    float4 bg[4];
    bg[0] = *reinterpret_cast<const float4*>(srcB + 0);
    bg[1] = *reinterpret_cast<const float4*>(srcB + 4);
    bg[2] = *reinterpret_cast<const float4*>(srcB + 8);
    bg[3] = *reinterpret_cast<const float4*>(srcB + 12);

    // ---- stage A row-half + norm ----
    {
        const float* src = x1 + (size_t)(by * 128 + row) * PP + half * 16;
        float partial = 0.f;
#pragma unroll
        for (int g = 0; g < 2; ++g) {
            float4 a = *reinterpret_cast<const float4*>(src + g * 8);
            float4 b = *reinterpret_cast<const float4*>(src + g * 8 + 4);
            float vs[8] = {a.x, a.y, a.z, a.w, b.x, b.y, b.z, b.w};
            bf16x8 hv, lv;
#pragma unroll
            for (int e = 0; e < 8; ++e) {
                float v = vs[e];
                partial = fmaf(v, v, partial);
                unsigned short h = f32_to_bf16_rtn(v);
                hv[e] = (short)h;
                lv[e] = (short)f32_to_bf16_rtn(v - __uint_as_float((unsigned)h << 16));
            }
            int off = row * LDA + half * 16 + g * 8;
            *reinterpret_cast<bf16x8*>(&Ah[off]) = hv;
            *reinterpret_cast<bf16x8*>(&Al[off]) = lv;
        }
        float full = partial + __shfl_xor(partial, 1);
        if (half == 0) *reinterpret_cast<float*>(&Ah[row * LDA + 32]) = full;
    }

    // ---- convert B row-half in registers ----
    bf16x8 bhv[2], blv[2];
    float bfull;
    {
        float partial = 0.f;
#pragma unroll
        for (int g = 0; g < 2; ++g) {
            float vs[8] = {bg[2*g].x, bg[2*g].y, bg[2*g].z, bg[2*g].w,
                           bg[2*g+1].x, bg[2*g+1].y, bg[2*g+1].z, bg[2*g+1].w};
            bf16x8 hv, lv;
#pragma unroll
            for (int e = 0; e < 8; ++e) {
                float v = vs[e];
                partial = fmaf(v, v, partial);
                unsigned short h = f32_to_bf16_rtn(v);
                hv[e] = (short)h;
                lv[e] = (short)f32_to_bf16_rtn(v - __uint_as_float((unsigned)h << 16));
            }
            bhv[g] = hv; blv[g] = lv;
        }
        bfull = partial + __shfl_xor(partial, 1);
    }

    // ---- B0 (rows 0..63) written pre-sync1 ----
    if (row < 64) {
#pragma unroll
        for (int g = 0; g < 2; ++g) {
            int off = row * LDA + half * 16 + g * 8;
            *reinterpret_cast<bf16x8*>(&Bh[off]) = bhv[g];
            *reinterpret_cast<bf16x8*>(&Bl[off]) = blv[g];
        }
        if (half == 0) *reinterpret_cast<float*>(&Bh[row * LDA + 32]) = bfull;
    }

    const float inv_rho2 = __expf(-2.f * log_rho[0]);
    const float ir2l2    = inv_rho2 * LOG2E;            // LOG2E * ir2
    const float nh       = -0.5f * ir2l2;               // -LOG2E * ir2 / 2
    const float ls2      = 2.f * LOG2E * log_sigma[0];  // log2(sigma)

    __syncthreads();

    // ---- B1 (rows 64..127) written post-sync1, consumed after sync2 ----
    if (row >= 64) {
#pragma unroll
        for (int g = 0; g < 2; ++g) {
            int off = row * LDA + half * 16 + g * 8;
            *reinterpret_cast<bf16x8*>(&Bh[off]) = bhv[g];
            *reinterpret_cast<bf16x8*>(&Bl[off]) = blv[g];
        }
        if (half == 0) *reinterpret_cast<float*>(&Bh[row * LDA + 32]) = bfull;
    }

    // ---------------- Phase 2 ----------------
    const int w    = t >> 6;   // wave 0..3 -> rows w*32..w*32+31
    const int l    = t & 63;
    const int lo16 = l & 15;   // output ROW within strip (swapped layout)
    const int kg   = l >> 4;   // output col-quad within tile / k-chunk

    bf16x8 ah[2], al[2];
    float xh[2];               // nh * xn for this lane's row in each strip
#pragma unroll
    for (int s = 0; s < 2; ++s) {
        int r   = w * 32 + s * 16 + lo16;
        int off = r * LDA + kg * 8;
        ah[s] = *reinterpret_cast<const bf16x8*>(&Ah[off]);
        al[s] = *reinterpret_cast<const bf16x8*>(&Al[off]);
        xh[s] = nh * *reinterpret_cast<const float*>(&Ah[r * LDA + 32]);
    }

    const int rbase = by * 128 + w * 32;
    const int cb0   = bx * 128;

    auto do_ct = [&](int ct) {
        int off = (ct * 16 + lo16) * LDA + kg * 8;
        bf16x8 bh = *reinterpret_cast<const bf16x8*>(&Bh[off]);
        bf16x8 bl = *reinterpret_cast<const bf16x8*>(&Bl[off]);
        float yb[4];
#pragma unroll
        for (int j = 0; j < 4; ++j)   // uniform across 16-lane group -> broadcast
            yb[j] = fmaf(nh, *reinterpret_cast<const float*>(&Bh[(ct * 16 + kg * 4 + j) * LDA + 32]), ls2);
        const int colbase = cb0 + ct * 16 + kg * 4;
#pragma unroll
        for (int s = 0; s < 2; ++s) {
            f32x4 acc = {0.f, 0.f, 0.f, 0.f};
            // swapped operands: reg indexes x2 (column) dim
            acc = __builtin_amdgcn_mfma_f32_16x16x32_bf16(bh, ah[s], acc, 0, 0, 0);
            acc = __builtin_amdgcn_mfma_f32_16x16x32_bf16(bh, al[s], acc, 0, 0, 0);
            acc = __builtin_amdgcn_mfma_f32_16x16x32_bf16(bl, ah[s], acc, 0, 0, 0);
            f32x4 K;
#pragma unroll
            for (int r = 0; r < 4; ++r) {
                float u = fmaf(ir2l2, acc[r], xh[s] + yb[r]);
                K[r] = exp2f(fminf(u, ls2));
            }
            const int orow = rbase + s * 16 + lo16;
            *reinterpret_cast<f32x4*>(&out[(size_t)orow * MM + colbase]) = K;
        }
    };

#pragma unroll
    for (int ct = 0; ct < 4; ++ct) do_ct(ct);
    __syncthreads();
#pragma unroll
    for (int ct = 4; ct < 8; ++ct) do_ct(ct);
}

extern "C" void kernel_launch(void* const* d_in, const int* in_sizes, int n_in,
                              void* d_out, int out_size, void* d_ws, size_t ws_size,
                              hipStream_t stream) {
    const float* x1        = (const float*)d_in[0];
    const float* x2        = (const float*)d_in[1];
    const float* log_rho   = (const float*)d_in[2];
    const float* log_sigma = (const float*)d_in[3];
    float* out = (float*)d_out;

    dim3 grid(MM / 128, NN / 128);   // 32 x 32 = 1024 blocks = 256 CU x 4
    eq_fused_mfma_kernel<<<grid, 256, 0, stream>>>(x1, x2, log_rho, log_sigma, out);
}